// Round 10
// baseline (209.081 us; speedup 1.0000x reference)
//
#include <hip/hip_runtime.h>
#include <math.h>

// PinSAGE fused pipeline, r10: minimal-register TLP edition.
// Theory: unified VGPR+AGPR budget (512/SIMD) capped all prior rounds at
// 2 waves/SIMD. Delete standing prefetch state, fit unified <= 128
// -> 4 waves/SIMD, 16 waves/CU; latency hidden by TLP alone.
// D=U=E=128, T=20 fixed; N, V from in_sizes.
//
// K0 prep:  WqT/WnT/WwT/WgT = bf16 transpose of weights (WT[n][k])
// K1:       H = relu(table @ Wn + bn) -> bf16 [V][128]   (blocks < splitH)
//           nodeh = relu(table[node_ids] @ Wq + bq) -> nh[:,0:128] (rest)
//           W 32 KB LDS (XOR-swizzled); per-wave 16-row tiles, no prefetch,
//           lb(256,4); grid 2048.
// K2 agg:   nh[:,128:256] = sum_t alpha * H[neigh]  (gather-FMA)
// K3 emb:   embb = relu(nh @ Ww + bw) bf16 + sumsq partials; K=256,
//           W 64 KB LDS (2 blocks/CU cap), 512 blocks.
// K4 final: out = relu(scale*(embb @ Wg) + bg) fp32; inline partials reduce;
//           W 32 KB LDS, lb(256,4), 1024 blocks.
//
// MFMA orientation (verified r3..r9): acc[mt] = mfma(wfrag, afrag, acc) ->
// lane l holds C[row = tile*16 + (l&15)][cols 16*mt + 4*(l>>4) + i].

using f32x4  = __attribute__((ext_vector_type(4))) float;
using short8 = __attribute__((ext_vector_type(8))) short;   // 8 bf16

__device__ __forceinline__ ushort f2bf(float f) {
    uint u = __float_as_uint(f);
    return (ushort)((u + 0x7fffu + ((u >> 16) & 1u)) >> 16);   // RNE
}
__device__ __forceinline__ float bf2f(ushort h) {
    return __uint_as_float((uint)h << 16);
}
__device__ __forceinline__ uint pk2(float lo, float hi) {
    return (uint)f2bf(lo) | ((uint)f2bf(hi) << 16);
}
__device__ __forceinline__ short8 pack8(f32x4 a, f32x4 b) {
    uint4 r;
    r.x = pk2(a[0], a[1]); r.y = pk2(a[2], a[3]);
    r.z = pk2(b[0], b[1]); r.w = pk2(b[2], b[3]);
    union { uint4 u; short8 s; } cv; cv.u = r; return cv.s;
}

// ---------------------------------------------------------------------------
__global__ __launch_bounds__(256)
void prep_weights(const float* __restrict__ Wq, const float* __restrict__ Wn,
                  const float* __restrict__ Ww, const float* __restrict__ Wg,
                  ushort* __restrict__ WqT, ushort* __restrict__ WnT,
                  ushort* __restrict__ WwT, ushort* __restrict__ WgT)
{
    int idx = blockIdx.x * 256 + threadIdx.x;   // 320 blocks -> 81920
    const float* W; ushort* WT; int K; int j = idx;
    if (j < 16384)      { W = Wq; WT = WqT; K = 128; }
    else if (j < 32768) { W = Wn; WT = WnT; K = 128; j -= 16384; }
    else if (j < 65536) { W = Ww; WT = WwT; K = 256; j -= 32768; }
    else                { W = Wg; WT = WgT; K = 128; j -= 65536; }
    int n = j & 127, k = j >> 7;
    WT[(size_t)n * K + k] = f2bf(W[j]);
}

// ---------------------------------------------------------------------------
// W staging + fragment read (XOR-swizzled: byte ^= (n&7)<<4 within row)
// ---------------------------------------------------------------------------
__device__ __forceinline__ void stage_w128(const ushort* __restrict__ WT,
                                           ushort* Wlds, int tid)
{
#pragma unroll
    for (int it = 0; it < 8; ++it) {
        int idx = it * 256 + tid, n = idx >> 4, o = idx & 15;
        uint4 v = *reinterpret_cast<const uint4*>(&WT[(size_t)n * 128 + 8 * o]);
        *reinterpret_cast<uint4*>((char*)Wlds + n * 256 + ((16 * o) ^ ((n & 7) << 4))) = v;
    }
}
__device__ __forceinline__ void stage_w256(const ushort* __restrict__ WT,
                                           ushort* Wlds, int tid)
{
#pragma unroll
    for (int it = 0; it < 16; ++it) {
        int idx = it * 256 + tid, n = idx >> 5, o = idx & 31;
        uint4 v = *reinterpret_cast<const uint4*>(&WT[(size_t)n * 256 + 8 * o]);
        *reinterpret_cast<uint4*>((char*)Wlds + n * 512 + ((16 * o) ^ ((n & 7) << 4))) = v;
    }
}
__device__ __forceinline__ short8 ldw(const ushort* Wlds, int rowbytes,
                                      int mt, int ks, int l16, int lh)
{
    return *reinterpret_cast<const short8*>(
        (const char*)Wlds + (16 * mt + l16) * rowbytes +
        ((64 * ks + 16 * lh) ^ ((l16 & 7) << 4)));
}

// ---------------------------------------------------------------------------
// K1: dual GEMM, W in LDS, per-wave 16-row tiles, NO standing prefetch state.
// Unified regs target <= 128 -> 4 waves/SIMD; 33 KB LDS -> 4 blocks/CU.
// ---------------------------------------------------------------------------
__global__ __launch_bounds__(256, 4)
void k1_w(const float* __restrict__ table, const int* __restrict__ node_ids,
          const ushort* __restrict__ WnT, const float* __restrict__ bn,
          const ushort* __restrict__ WqT, const float* __restrict__ bq,
          ushort* __restrict__ H, ushort* __restrict__ nh,
          int V, int N, int splitH)
{
    __shared__ __align__(16) ushort Wlds[128 * 128];   // 32 KB
    __shared__ __align__(16) float blds[128];
    const int tid = threadIdx.x;
    const int w = tid >> 6, l = tid & 63, l16 = l & 15, lh = l >> 4;
    const bool isH = (int)blockIdx.x < splitH;

    stage_w128(isH ? WnT : WqT, Wlds, tid);
    if (tid < 128) blds[tid] = (isH ? bn : bq)[tid];
    __syncthreads();

    const int M   = isH ? V : N;
    ushort* out   = isH ? H : nh;
    const int ldo = isH ? 128 : 256;
    const int nt  = (M + 15) >> 4;
    const int wid    = (isH ? (int)blockIdx.x : (int)blockIdx.x - splitH) * 4 + w;
    const int nwaves = (isH ? splitH : (int)gridDim.x - splitH) * 4;

    for (int tile = wid; tile < nt; tile += nwaves) {
        const int row = tile * 16 + l16;
        int g = (row < M) ? row : (M - 1);
        if (!isH) g = node_ids[g];
        const float* rp = table + (size_t)g * 128 + 8 * lh;

        f32x4 f[8];                        // transient: dies into a[]
#pragma unroll
        for (int ks = 0; ks < 4; ++ks) {
            f[2 * ks]     = *reinterpret_cast<const f32x4*>(rp + 32 * ks);
            f[2 * ks + 1] = *reinterpret_cast<const f32x4*>(rp + 32 * ks + 4);
        }
        short8 a[4];
#pragma unroll
        for (int ks = 0; ks < 4; ++ks) a[ks] = pack8(f[2 * ks], f[2 * ks + 1]);

        f32x4 acc[8];
#pragma unroll
        for (int mt = 0; mt < 8; ++mt)
#pragma unroll
            for (int i = 0; i < 4; ++i) acc[mt][i] = 0.f;
#pragma unroll
        for (int ks = 0; ks < 4; ++ks)
#pragma unroll
            for (int mt = 0; mt < 8; ++mt)
                acc[mt] = __builtin_amdgcn_mfma_f32_16x16x32_bf16(
                    ldw(Wlds, 256, mt, ks, l16, lh), a[ks], acc[mt], 0, 0, 0);

        if (row < M) {
#pragma unroll
            for (int mt = 0; mt < 8; ++mt) {
                f32x4 bv = *reinterpret_cast<const f32x4*>(&blds[16 * mt + 4 * lh]);
                uint2 q;
                q.x = pk2(fmaxf(acc[mt][0] + bv[0], 0.f), fmaxf(acc[mt][1] + bv[1], 0.f));
                q.y = pk2(fmaxf(acc[mt][2] + bv[2], 0.f), fmaxf(acc[mt][3] + bv[3], 0.f));
                *reinterpret_cast<uint2*>(&out[(size_t)row * ldo + 16 * mt + 4 * lh]) = q;
            }
        }
    }
}

// ---------------------------------------------------------------------------
// K2: agg[n][:] = sum_t alpha[n,t] * H[neigh_ids[n,t]][:]
// ---------------------------------------------------------------------------
__global__ __launch_bounds__(256)
void agg_bf16(const ushort* __restrict__ H,
              const int* __restrict__ nids,
              const float* __restrict__ alpha,
              ushort* __restrict__ outb,     // nh + 128, row stride 256
              int N)
{
    const int n   = blockIdx.x * 16 + (threadIdx.x >> 4);
    const int l16 = threadIdx.x & 15;
    if (n >= N) return;

    const int*   idp = &nids[n * 20];
    const float* alp = &alpha[n * 20];
    float a[8];
#pragma unroll
    for (int j = 0; j < 8; ++j) a[j] = 0.f;
#pragma unroll
    for (int t = 0; t < 20; ++t) {
        const int   id = idp[t];
        const float al = alp[t];
        uint4 h = *reinterpret_cast<const uint4*>(&H[(size_t)id * 128 + 8 * l16]);
        a[0] = fmaf(al, bf2f((ushort)(h.x & 0xffff)), a[0]);
        a[1] = fmaf(al, bf2f((ushort)(h.x >> 16)),    a[1]);
        a[2] = fmaf(al, bf2f((ushort)(h.y & 0xffff)), a[2]);
        a[3] = fmaf(al, bf2f((ushort)(h.y >> 16)),    a[3]);
        a[4] = fmaf(al, bf2f((ushort)(h.z & 0xffff)), a[4]);
        a[5] = fmaf(al, bf2f((ushort)(h.z >> 16)),    a[5]);
        a[6] = fmaf(al, bf2f((ushort)(h.w & 0xffff)), a[6]);
        a[7] = fmaf(al, bf2f((ushort)(h.w >> 16)),    a[7]);
    }
    uint4 p;
    p.x = pk2(a[0], a[1]); p.y = pk2(a[2], a[3]);
    p.z = pk2(a[4], a[5]); p.w = pk2(a[6], a[7]);
    *reinterpret_cast<uint4*>(&outb[(size_t)n * 256 + 8 * l16]) = p;
}

// ---------------------------------------------------------------------------
// K3: emb = relu(nh @ Ww + bw) -> bf16 embb + per-block sumsq. K=256,
// W 64 KB LDS (2 blocks/CU), no prefetch.
// ---------------------------------------------------------------------------
__global__ __launch_bounds__(256, 2)
void k3_emb(const ushort* __restrict__ nh, const ushort* __restrict__ WwT,
            const float* __restrict__ bw, ushort* __restrict__ embb,
            float* __restrict__ partials, int N)
{
    __shared__ __align__(16) ushort Wlds[128 * 256];   // 64 KB
    __shared__ __align__(16) float blds[128];
    __shared__ float red[256];
    const int tid = threadIdx.x;
    const int w = tid >> 6, l = tid & 63, l16 = l & 15, lh = l >> 4;

    stage_w256(WwT, Wlds, tid);
    if (tid < 128) blds[tid] = bw[tid];
    __syncthreads();

    const int nt = (N + 15) >> 4;
    const int wid = (int)blockIdx.x * 4 + w;
    const int nwaves = (int)gridDim.x * 4;
    float ssq = 0.f;

    for (int tile = wid; tile < nt; tile += nwaves) {
        const int row = tile * 16 + l16;
        const int g = (row < N) ? row : (N - 1);
        const ushort* rp = nh + (size_t)g * 256 + 8 * lh;
        short8 a[8];
#pragma unroll
        for (int ks = 0; ks < 8; ++ks)
            a[ks] = *reinterpret_cast<const short8*>(rp + 32 * ks);

        f32x4 acc[8];
#pragma unroll
        for (int mt = 0; mt < 8; ++mt)
#pragma unroll
            for (int i = 0; i < 4; ++i) acc[mt][i] = 0.f;
#pragma unroll
        for (int ks = 0; ks < 8; ++ks)
#pragma unroll
            for (int mt = 0; mt < 8; ++mt)
                acc[mt] = __builtin_amdgcn_mfma_f32_16x16x32_bf16(
                    ldw(Wlds, 512, mt, ks, l16, lh), a[ks], acc[mt], 0, 0, 0);

        const bool ok = row < N;
#pragma unroll
        for (int mt = 0; mt < 8; ++mt) {
            f32x4 bv = *reinterpret_cast<const f32x4*>(&blds[16 * mt + 4 * lh]);
            f32x4 v;
#pragma unroll
            for (int i = 0; i < 4; ++i) v[i] = fmaxf(acc[mt][i] + bv[i], 0.f);
            if (ok) {
                ssq += v[0] * v[0] + v[1] * v[1] + v[2] * v[2] + v[3] * v[3];
                uint2 q; q.x = pk2(v[0], v[1]); q.y = pk2(v[2], v[3]);
                *reinterpret_cast<uint2*>(&embb[(size_t)row * 128 + 16 * mt + 4 * lh]) = q;
            }
        }
    }

    red[tid] = ssq;
    __syncthreads();
    for (int st = 128; st > 0; st >>= 1) {
        if (tid < st) red[tid] += red[tid + st];
        __syncthreads();
    }
    if (tid == 0) partials[blockIdx.x] = red[0];
}

// ---------------------------------------------------------------------------
// K4: out = relu(scale*(embb @ Wg) + bg) fp32; scale reduced inline.
// W 32 KB LDS, lb(256,4), no prefetch.
// ---------------------------------------------------------------------------
__global__ __launch_bounds__(256, 4)
void k4_final(const ushort* __restrict__ embb, const ushort* __restrict__ WgT,
              const float* __restrict__ bg, const float* __restrict__ partials,
              int P, float* __restrict__ outp, int N)
{
    __shared__ __align__(16) ushort Wlds[128 * 128];   // 32 KB
    __shared__ __align__(16) float blds[128];
    __shared__ float red[256];
    __shared__ float s_scale;
    const int tid = threadIdx.x;
    const int w = tid >> 6, l = tid & 63, l16 = l & 15, lh = l >> 4;

    stage_w128(WgT, Wlds, tid);
    if (tid < 128) blds[tid] = bg[tid];
    float s = 0.f;
    for (int i = tid; i < P; i += 256) s += partials[i];
    red[tid] = s;
    __syncthreads();
    for (int st = 128; st > 0; st >>= 1) {
        if (tid < st) red[tid] += red[tid + st];
        __syncthreads();
    }
    if (tid == 0) s_scale = 1.0f / sqrtf(red[0]);
    __syncthreads();
    const float scale = s_scale;

    const int nt = (N + 15) >> 4;
    const int wid = (int)blockIdx.x * 4 + w;
    const int nwaves = (int)gridDim.x * 4;

    for (int tile = wid; tile < nt; tile += nwaves) {
        const int row = tile * 16 + l16;
        const int g = (row < N) ? row : (N - 1);
        const ushort* rp = embb + (size_t)g * 128 + 8 * lh;
        short8 a[4];
#pragma unroll
        for (int ks = 0; ks < 4; ++ks)
            a[ks] = *reinterpret_cast<const short8*>(rp + 32 * ks);

        f32x4 acc[8];
#pragma unroll
        for (int mt = 0; mt < 8; ++mt)
#pragma unroll
            for (int i = 0; i < 4; ++i) acc[mt][i] = 0.f;
#pragma unroll
        for (int ks = 0; ks < 4; ++ks)
#pragma unroll
            for (int mt = 0; mt < 8; ++mt)
                acc[mt] = __builtin_amdgcn_mfma_f32_16x16x32_bf16(
                    ldw(Wlds, 256, mt, ks, l16, lh), a[ks], acc[mt], 0, 0, 0);

        if (row < N) {
#pragma unroll
            for (int mt = 0; mt < 8; ++mt) {
                f32x4 bv = *reinterpret_cast<const f32x4*>(&blds[16 * mt + 4 * lh]);
                f32x4 v;
#pragma unroll
                for (int i = 0; i < 4; ++i)
                    v[i] = fmaxf(fmaf(acc[mt][i], scale, bv[i]), 0.f);
                *reinterpret_cast<f32x4*>(&outp[(size_t)row * 128 + 16 * mt + 4 * lh]) = v;
            }
        }
    }
}

// ---------------------------------------------------------------------------
extern "C" void kernel_launch(void* const* d_in, const int* in_sizes, int n_in,
                              void* d_out, int out_size, void* d_ws, size_t ws_size,
                              hipStream_t stream)
{
    const int*   node_ids  = (const int*)  d_in[0];
    const int*   neigh_ids = (const int*)  d_in[1];
    const float* alpha     = (const float*)d_in[2];
    const float* table     = (const float*)d_in[3];
    const float* Wq        = (const float*)d_in[4];
    const float* bq        = (const float*)d_in[5];
    const float* Wn        = (const float*)d_in[6];
    const float* bn        = (const float*)d_in[7];
    const float* Ww        = (const float*)d_in[8];
    const float* bw        = (const float*)d_in[9];
    const float* Wg        = (const float*)d_in[10];
    const float* bg        = (const float*)d_in[11];

    const int N = in_sizes[0];            // 50000
    const int V = in_sizes[3] / 128;      // 200000
    float* out = (float*)d_out;

    // workspace layout
    ushort* H    = (ushort*)d_ws;                 // [V][128] bf16
    ushort* nh   = H    + (size_t)V * 128;        // [N][256] = [node_h | agg]
    ushort* embb = nh   + (size_t)N * 256;        // [N][128]
    ushort* WqT  = embb + (size_t)N * 128;
    ushort* WnT  = WqT  + 16384;
    ushort* WwT  = WnT  + 16384;
    ushort* WgT  = WwT  + 32768;
    float*  partials = (float*)(WgT + 16384);     // 1024
    float*  scale    = partials + 1024;

    const size_t need = (size_t)((char*)(scale + 16) - (char*)d_ws);
    if (ws_size < need) return;

    // K1 grid: 2048 blocks, split by 16-row tile counts
    const int G1 = 2048;
    const long long tH = (V + 15) / 16, tN = (N + 15) / 16;
    int splitH = (int)((G1 * tH) / (tH + tN));
    if (splitH < 1) splitH = 1;
    if (splitH > G1 - 1) splitH = G1 - 1;

    const int G3 = 512;
    const int G4 = 1024;

    prep_weights<<<320, 256, 0, stream>>>(Wq, Wn, Ww, Wg, WqT, WnT, WwT, WgT);
    k1_w<<<G1, 256, 0, stream>>>(table, node_ids, WnT, bn, WqT, bq,
                                 H, nh, V, N, splitH);
    agg_bf16<<<(N + 15) / 16, 256, 0, stream>>>(H, neigh_ids, alpha, nh + 128, N);
    k3_emb<<<G3, 256, 0, stream>>>(nh, WwT, bw, embb, partials, N);
    k4_final<<<G4, 256, 0, stream>>>(embb, WgT, bg, partials, G3, out, N);
}

// Round 11
// 112.523 us; speedup vs baseline: 1.8581x; 1.8581x over previous
//
#include <hip/hip_runtime.h>
#include <math.h>

// PinSAGE fused pipeline, r11: k1 via global_load_lds DMA double-buffer
// (zero-register pipeline depth); rest of pipeline = r5 proven kernels.
// D=U=E=128, T=20 fixed; N, V from in_sizes.
//
// K0 prep:  WqT/WnT/WwT/WgT = bf16 transpose of weights (WT[n][k])
// K1 async: H = relu(table @ Wn + bn) -> bf16 [V][128]   (blocks < splitH)
//           nodeh = relu(table[node_ids] @ Wq + bq) -> nh[:,0:128] (rest)
//           128-thr blocks; W 32 KB LDS; A tiles 32 rows fp32, 2x16 KB
//           double-buffer staged by global_load_lds (pre-swizzled source,
//           swizzled ds_read -- rule #21 both-sides). 2-phase: stage t+1,
//           compute t, __syncthreads (vmcnt drain) per iteration.
// K2 agg:   nh[:,128:256] = sum_t alpha * H[neigh]  (gather-FMA)
// K3 emb:   embb = relu(nh @ Ww + bw) bf16 + sumsq partials (r5 kernel)
// K4 norm:  scale = 1/||emb||_F
// K5 final: out = relu(scale*(embb @ Wg) + bg) fp32 (r5 kernel)
//
// MFMA orientation (verified r3..r10): acc[mt] = mfma(wfrag, afrag, acc) ->
// lane l holds C[row = 16*wt + (l&15)][cols 16*mt + 4*(l>>4) + i].

using f32x4  = __attribute__((ext_vector_type(4))) float;
using short8 = __attribute__((ext_vector_type(8))) short;   // 8 bf16

typedef const void __attribute__((address_space(1))) gvoid_t;
typedef void       __attribute__((address_space(3))) svoid_t;

__device__ __forceinline__ void gload16(const void* g, void* l) {
    __builtin_amdgcn_global_load_lds((gvoid_t*)g, (svoid_t*)l, 16, 0, 0);
}

__device__ __forceinline__ ushort f2bf(float f) {
    uint u = __float_as_uint(f);
    return (ushort)((u + 0x7fffu + ((u >> 16) & 1u)) >> 16);   // RNE
}
__device__ __forceinline__ float bf2f(ushort h) {
    return __uint_as_float((uint)h << 16);
}
__device__ __forceinline__ uint pk2(float lo, float hi) {
    return (uint)f2bf(lo) | ((uint)f2bf(hi) << 16);
}
__device__ __forceinline__ short8 pack8(f32x4 a, f32x4 b) {
    uint4 r;
    r.x = pk2(a[0], a[1]); r.y = pk2(a[2], a[3]);
    r.z = pk2(b[0], b[1]); r.w = pk2(b[2], b[3]);
    union { uint4 u; short8 s; } cv; cv.u = r; return cv.s;
}

// ---------------------------------------------------------------------------
__global__ __launch_bounds__(256)
void prep_weights(const float* __restrict__ Wq, const float* __restrict__ Wn,
                  const float* __restrict__ Ww, const float* __restrict__ Wg,
                  ushort* __restrict__ WqT, ushort* __restrict__ WnT,
                  ushort* __restrict__ WwT, ushort* __restrict__ WgT)
{
    int idx = blockIdx.x * 256 + threadIdx.x;   // 320 blocks -> 81920
    const float* W; ushort* WT; int K; int j = idx;
    if (j < 16384)      { W = Wq; WT = WqT; K = 128; }
    else if (j < 32768) { W = Wn; WT = WnT; K = 128; j -= 16384; }
    else if (j < 65536) { W = Ww; WT = WwT; K = 256; j -= 32768; }
    else                { W = Wg; WT = WgT; K = 128; j -= 65536; }
    int n = j & 127, k = j >> 7;
    WT[(size_t)n * K + k] = f2bf(W[j]);
}

// ---------------------------------------------------------------------------
// K1: DMA-pipelined dual GEMM.
// ---------------------------------------------------------------------------
template<bool GATHER>
__device__ __forceinline__ void stage_tile(const float* __restrict__ table,
                                           const int* __restrict__ gidx,
                                           float* Ab, int tile, int M,
                                           int w, int l)
{
#pragma unroll
    for (int j = 0; j < 8; ++j) {
        const int u   = j * 2 + w;           // KB unit 0..15, wave-uniform
        const int idx = u * 64 + l;          // 16B chunk 0..1023
        const int r   = idx >> 5;            // tile-local row 0..31
        const int c   = idx & 31;            // 16B chunk within 512B row
        int grow = tile * 32 + r;
        if (grow > M - 1) grow = M - 1;
        const int g = GATHER ? gidx[grow] : grow;
        const char* src = (const char*)table + (size_t)g * 512
                        + (size_t)((c * 16) ^ ((r & 7) << 4));
        gload16(src, (char*)Ab + u * 1024);  // HW: dest + lane*16
    }
}

__global__ __launch_bounds__(128, 2)
void k1_async(const float* __restrict__ table, const int* __restrict__ node_ids,
              const ushort* __restrict__ WnT, const float* __restrict__ bn,
              const ushort* __restrict__ WqT, const float* __restrict__ bq,
              ushort* __restrict__ H, ushort* __restrict__ nh,
              int V, int N, int splitH)
{
    __shared__ __align__(16) ushort Wlds[128 * 128];     // 32 KB, swizzled
    __shared__ __align__(16) float  Abuf[2][32 * 128];   // 2 x 16 KB, dbuf
    __shared__ __align__(16) float  blds[128];
    const int tid = threadIdx.x;            // 128 threads = 2 waves
    const int w = tid >> 6, l = tid & 63, l16 = l & 15, lh = l >> 4;
    const bool isH = (int)blockIdx.x < splitH;

    // --- stage W (swizzled) + bias, once ---
    const ushort* WT = isH ? WnT : WqT;
#pragma unroll
    for (int it = 0; it < 16; ++it) {
        int idx = it * 128 + tid, n = idx >> 4, o = idx & 15;
        uint4 v = *reinterpret_cast<const uint4*>(&WT[(size_t)n * 128 + 8 * o]);
        *reinterpret_cast<uint4*>((char*)Wlds + n * 256 + ((16 * o) ^ ((n & 7) << 4))) = v;
    }
    blds[tid] = (isH ? bn : bq)[tid];

    const int M   = isH ? V : N;
    ushort* out   = isH ? H : nh;
    const int ldo = isH ? 128 : 256;
    const int nt  = (M + 31) >> 5;          // 32-row tiles
    const int bidx = isH ? (int)blockIdx.x : (int)blockIdx.x - splitH;
    const int nblk = isH ? splitH : (int)gridDim.x - splitH;

    int tile = bidx;
    if (tile < nt) {
        if (isH) stage_tile<false>(table, nullptr,  Abuf[0], tile, M, w, l);
        else     stage_tile<true >(table, node_ids, Abuf[0], tile, M, w, l);
    }
    __syncthreads();                        // vmcnt(0): buf0 + W ready

    int cur = 0;
    const int r = 16 * w + l16;             // tile-local row this lane owns
    for (; tile < nt; tile += nblk) {
        const int nxt = tile + nblk;
        if (nxt < nt) {                     // DMA next tile into other buffer
            if (isH) stage_tile<false>(table, nullptr,  Abuf[cur ^ 1], nxt, M, w, l);
            else     stage_tile<true >(table, node_ids, Abuf[cur ^ 1], nxt, M, w, l);
        }

        // --- compute current tile from LDS (swizzled reads) ---
        const char* Ab = (const char*)Abuf[cur];
        short8 a[4];
#pragma unroll
        for (int ks = 0; ks < 4; ++ks) {
            f32x4 b0 = *reinterpret_cast<const f32x4*>(
                Ab + r * 512 + ((ks * 128 + lh * 32)      ^ ((r & 7) << 4)));
            f32x4 b1 = *reinterpret_cast<const f32x4*>(
                Ab + r * 512 + ((ks * 128 + lh * 32 + 16) ^ ((r & 7) << 4)));
            a[ks] = pack8(b0, b1);
        }

        f32x4 acc[8];
#pragma unroll
        for (int mt = 0; mt < 8; ++mt)
#pragma unroll
            for (int i = 0; i < 4; ++i) acc[mt][i] = 0.f;
#pragma unroll
        for (int ks = 0; ks < 4; ++ks)
#pragma unroll
            for (int mt = 0; mt < 8; ++mt) {
                short8 wf = *reinterpret_cast<const short8*>(
                    (const char*)Wlds + (16 * mt + l16) * 256 +
                    ((64 * ks + 16 * lh) ^ ((l16 & 7) << 4)));
                acc[mt] = __builtin_amdgcn_mfma_f32_16x16x32_bf16(wf, a[ks], acc[mt], 0, 0, 0);
            }

        const int grow = tile * 32 + r;
        if (grow < M) {
#pragma unroll
            for (int mt = 0; mt < 8; ++mt) {
                f32x4 bv = *reinterpret_cast<const f32x4*>(&blds[16 * mt + 4 * lh]);
                uint2 q;
                q.x = pk2(fmaxf(acc[mt][0] + bv[0], 0.f), fmaxf(acc[mt][1] + bv[1], 0.f));
                q.y = pk2(fmaxf(acc[mt][2] + bv[2], 0.f), fmaxf(acc[mt][3] + bv[3], 0.f));
                *reinterpret_cast<uint2*>(&out[(size_t)grow * ldo + 16 * mt + 4 * lh]) = q;
            }
        }
        __syncthreads();                    // vmcnt(0): next buffer staged
        cur ^= 1;
    }
}

// ---------------------------------------------------------------------------
// K2: agg[n][:] = sum_t alpha[n,t] * H[neigh_ids[n,t]][:]
// ---------------------------------------------------------------------------
__global__ __launch_bounds__(256)
void agg_bf16(const ushort* __restrict__ H,
              const int* __restrict__ nids,
              const float* __restrict__ alpha,
              ushort* __restrict__ outb,     // nh + 128, row stride 256
              int N)
{
    const int n   = blockIdx.x * 16 + (threadIdx.x >> 4);
    const int l16 = threadIdx.x & 15;
    if (n >= N) return;

    const int*   idp = &nids[n * 20];
    const float* alp = &alpha[n * 20];
    float a[8];
#pragma unroll
    for (int j = 0; j < 8; ++j) a[j] = 0.f;
#pragma unroll
    for (int t = 0; t < 20; ++t) {
        const int   id = idp[t];
        const float al = alp[t];
        uint4 h = *reinterpret_cast<const uint4*>(&H[(size_t)id * 128 + 8 * l16]);
        a[0] = fmaf(al, bf2f((ushort)(h.x & 0xffff)), a[0]);
        a[1] = fmaf(al, bf2f((ushort)(h.x >> 16)),    a[1]);
        a[2] = fmaf(al, bf2f((ushort)(h.y & 0xffff)), a[2]);
        a[3] = fmaf(al, bf2f((ushort)(h.y >> 16)),    a[3]);
        a[4] = fmaf(al, bf2f((ushort)(h.z & 0xffff)), a[4]);
        a[5] = fmaf(al, bf2f((ushort)(h.z >> 16)),    a[5]);
        a[6] = fmaf(al, bf2f((ushort)(h.w & 0xffff)), a[6]);
        a[7] = fmaf(al, bf2f((ushort)(h.w >> 16)),    a[7]);
    }
    uint4 p;
    p.x = pk2(a[0], a[1]); p.y = pk2(a[2], a[3]);
    p.z = pk2(a[4], a[5]); p.w = pk2(a[6], a[7]);
    *reinterpret_cast<uint4*>(&outb[(size_t)n * 256 + 8 * l16]) = p;
}

// ---------------------------------------------------------------------------
// r5 LDS-staged MFMA GEMM (proven) -- K3 (emb) and K5 (final).
// ---------------------------------------------------------------------------
template<int KTOT, bool GATHER, bool ABF16, bool SUMSQ, bool SCALE, bool OUTBF16>
__global__ __launch_bounds__(256, 2)
void mfma_gemm(const void* __restrict__ Av, int lda,
               const int* __restrict__ gidx,
               const ushort* __restrict__ WT,   // [128][KTOT] bf16 pre-transposed
               const float* __restrict__ bias,
               void* __restrict__ outv, int ldo, int M,
               float* __restrict__ partials,
               const float* __restrict__ scale_ptr)
{
    __shared__ __align__(16) char smem[65536];  // A: [0,32K)  B: [32K,64K)
    __shared__ float red[256];
    char* Bbase = smem + 32768;

    const int tid = threadIdx.x;
    const int w   = tid >> 6;
    const int l   = tid & 63;
    const int l16 = l & 15, lh = l >> 4;
    const int brow = blockIdx.x * 128;

    f32x4 acc[2][8];
#pragma unroll
    for (int fr = 0; fr < 2; ++fr)
#pragma unroll
        for (int fc = 0; fc < 8; ++fc)
#pragma unroll
            for (int i = 0; i < 4; ++i) acc[fr][fc][i] = 0.f;

    for (int k0 = 0; k0 < KTOT; k0 += 128) {
        if (ABF16) {
            const ushort* A = (const ushort*)Av;
#pragma unroll
            for (int it = 0; it < 8; ++it) {
                int idx = it * 256 + tid;
                int r = idx >> 4, o = idx & 15;
                int row = brow + r; int grow = (row < M) ? row : (M - 1);
                if (GATHER) grow = gidx[grow];
                uint4 v = *reinterpret_cast<const uint4*>(&A[(size_t)grow * lda + k0 + 8 * o]);
                *reinterpret_cast<uint4*>(smem + r * 256 + ((16 * o) ^ ((r & 7) << 4))) = v;
            }
        } else {
            const float* A = (const float*)Av;
#pragma unroll
            for (int it = 0; it < 16; ++it) {
                int idx = it * 256 + tid;
                int r = idx >> 5, q = idx & 31;
                int row = brow + r; int grow = (row < M) ? row : (M - 1);
                if (GATHER) grow = gidx[grow];
                float4 v = *reinterpret_cast<const float4*>(&A[(size_t)grow * lda + k0 + 4 * q]);
                uint2 p;
                p.x = pk2(v.x, v.y);
                p.y = pk2(v.z, v.w);
                *reinterpret_cast<uint2*>(smem + r * 256 + ((8 * q) ^ ((r & 7) << 4))) = p;
            }
        }
#pragma unroll
        for (int it = 0; it < 8; ++it) {
            int idx = it * 256 + tid;
            int n = idx >> 4, o = idx & 15;
            uint4 v = *reinterpret_cast<const uint4*>(&WT[(size_t)n * KTOT + k0 + 8 * o]);
            *reinterpret_cast<uint4*>(Bbase + n * 256 + ((16 * o) ^ ((n & 7) << 4))) = v;
        }
        __syncthreads();

        const int r0 = 32 * w + l16;
        const int r1 = r0 + 16;
#pragma unroll
        for (int ks = 0; ks < 4; ++ks) {
            const int kb = 64 * ks + 16 * lh;
            short8 a0 = *reinterpret_cast<const short8*>(
                smem + r0 * 256 + (kb ^ ((r0 & 7) << 4)));
            short8 a1 = *reinterpret_cast<const short8*>(
                smem + r1 * 256 + (kb ^ ((r1 & 7) << 4)));
#pragma unroll
            for (int fc = 0; fc < 8; ++fc) {
                const int nn = 16 * fc + l16;
                short8 b = *reinterpret_cast<const short8*>(
                    Bbase + nn * 256 + (kb ^ ((nn & 7) << 4)));
                acc[0][fc] = __builtin_amdgcn_mfma_f32_16x16x32_bf16(a0, b, acc[0][fc], 0, 0, 0);
                acc[1][fc] = __builtin_amdgcn_mfma_f32_16x16x32_bf16(a1, b, acc[1][fc], 0, 0, 0);
            }
        }
        __syncthreads();
    }

    const float scale = SCALE ? scale_ptr[0] : 1.0f;
    float bloc[8];
#pragma unroll
    for (int fc = 0; fc < 8; ++fc) bloc[fc] = bias[16 * fc + l16];

    float ssq = 0.f;
#pragma unroll
    for (int fr = 0; fr < 2; ++fr)
#pragma unroll
        for (int fc = 0; fc < 8; ++fc)
#pragma unroll
            for (int i = 0; i < 4; ++i) {
                const int r   = 32 * w + 16 * fr + 4 * lh + i;
                const int col = 16 * fc + l16;
                float v = fmaxf(fmaf(acc[fr][fc][i], scale, bloc[fc]), 0.f);
                if (SUMSQ) { if (brow + r < M) ssq += v * v; }
                if (OUTBF16) ((ushort*)smem)[r * 128 + col] = f2bf(v);
                else         ((float*)smem)[r * 128 + col] = v;
            }
    __syncthreads();

    if (OUTBF16) {
        ushort* out = (ushort*)outv;
#pragma unroll
        for (int it = 0; it < 8; ++it) {
            int idx = it * 256 + tid;
            int r = idx >> 4, o = idx & 15;
            if (brow + r < M)
                *reinterpret_cast<uint4*>(&out[(size_t)(brow + r) * ldo + 8 * o]) =
                    *reinterpret_cast<const uint4*>((ushort*)smem + r * 128 + 8 * o);
        }
    } else {
        float* out = (float*)outv;
#pragma unroll
        for (int it = 0; it < 16; ++it) {
            int idx = it * 256 + tid;
            int r = idx >> 5, q = idx & 31;
            if (brow + r < M)
                *reinterpret_cast<float4*>(&out[(size_t)(brow + r) * ldo + 4 * q]) =
                    *reinterpret_cast<const float4*>((float*)smem + r * 128 + 4 * q);
        }
    }

    if (SUMSQ) {
        red[tid] = ssq;
        __syncthreads();
        for (int st = 128; st > 0; st >>= 1) {
            if (tid < st) red[tid] += red[tid + st];
            __syncthreads();
        }
        if (tid == 0) partials[blockIdx.x] = red[0];
    }
}

// ---------------------------------------------------------------------------
__global__ void reduce_norm(const float* __restrict__ partials, int n,
                            float* __restrict__ scale)
{
    __shared__ float red[256];
    float s = 0.f;
    for (int i = threadIdx.x; i < n; i += 256) s += partials[i];
    red[threadIdx.x] = s;
    __syncthreads();
    for (int st = 128; st > 0; st >>= 1) {
        if (threadIdx.x < st) red[threadIdx.x] += red[threadIdx.x + st];
        __syncthreads();
    }
    if (threadIdx.x == 0) scale[0] = 1.0f / sqrtf(red[0]);
}

// ---------------------------------------------------------------------------
extern "C" void kernel_launch(void* const* d_in, const int* in_sizes, int n_in,
                              void* d_out, int out_size, void* d_ws, size_t ws_size,
                              hipStream_t stream)
{
    const int*   node_ids  = (const int*)  d_in[0];
    const int*   neigh_ids = (const int*)  d_in[1];
    const float* alpha     = (const float*)d_in[2];
    const float* table     = (const float*)d_in[3];
    const float* Wq        = (const float*)d_in[4];
    const float* bq        = (const float*)d_in[5];
    const float* Wn        = (const float*)d_in[6];
    const float* bn        = (const float*)d_in[7];
    const float* Ww        = (const float*)d_in[8];
    const float* bw        = (const float*)d_in[9];
    const float* Wg        = (const float*)d_in[10];
    const float* bg        = (const float*)d_in[11];

    const int N = in_sizes[0];            // 50000
    const int V = in_sizes[3] / 128;      // 200000
    float* out = (float*)d_out;

    // workspace layout
    ushort* H    = (ushort*)d_ws;                 // [V][128] bf16
    ushort* nh   = H    + (size_t)V * 128;        // [N][256] = [node_h | agg]
    ushort* embb = nh   + (size_t)N * 256;        // [N][128]
    ushort* WqT  = embb + (size_t)N * 128;
    ushort* WnT  = WqT  + 16384;
    ushort* WwT  = WnT  + 16384;
    ushort* WgT  = WwT  + 32768;
    float*  partials = (float*)(WgT + 16384);     // 512
    float*  scale    = partials + 512;

    const size_t need = (size_t)((char*)(scale + 16) - (char*)d_ws);
    if (ws_size < need) return;

    const int nblkN = (N + 127) / 128;

    // K1 grid: 512 blocks x 128 thr (2 blocks/CU at 66 KB LDS),
    // split by 32-row tile counts.
    const int G1 = 512;
    const long long tH = (V + 31) / 32, tN = (N + 31) / 32;
    int splitH = (int)((G1 * tH) / (tH + tN));
    if (splitH < 1) splitH = 1;
    if (splitH > G1 - 1) splitH = G1 - 1;

    prep_weights<<<320, 256, 0, stream>>>(Wq, Wn, Ww, Wg, WqT, WnT, WwT, WgT);
    k1_async<<<G1, 128, 0, stream>>>(table, node_ids, WnT, bn, WqT, bq,
                                     H, nh, V, N, splitH);
    agg_bf16<<<(N + 15) / 16, 256, 0, stream>>>(H, neigh_ids, alpha, nh + 128, N);
    mfma_gemm<256, false, true, true, false, true><<<nblkN, 256, 0, stream>>>(
        nh, 256, nullptr, WwT, bw, embb, 128, N, partials, nullptr);
    reduce_norm<<<1, 256, 0, stream>>>(partials, nblkN, scale);
    mfma_gemm<128, false, true, false, true, false><<<nblkN, 256, 0, stream>>>(
        embb, 128, nullptr, WgT, bg, out, 128, N, nullptr, scale);
}